// Round 4
// baseline (578.030 us; speedup 1.0000x reference)
//
#include <hip/hip_runtime.h>
#include <math.h>

// ---------- problem constants ----------
// B=16, F=256, C=64, H=64, W=64, N_E=512. Inputs fp32, outputs fp32.
// tokens: rows r=(b*64+c)*64+h of 64 w-values; 65536 tokens total.
// Strategy: fp32 main pass; tokens with top-2 distance gap < MARGIN are
// re-resolved in a fully-fp64 refine pass (matches the np float64 ref argmin).

#define CAP    4096
#define MARGIN 4e-3f

// ---------- workspace layout (float offsets; doubles at even offsets) ----------
#define WS_WT   512      // [256*64]  W' float [f][o]
#define WS_BP   16896    // [64]      fused bias float
#define WS_EN   16960    // [512]     code norms
#define WS_E2   17472    // [512]     code sq-norms
#define WS_ACC  17984    // [8]       accumulators: 0=mse 1=var 2=tmd
#define WS_CNT  17992    // [8]       int counter region
#define WS_WL   18000    // [4096]    int worklist
#define WS_EFT  22096    // [64*512]  embedding transposed float [k][n]
#define WS_AD   54864    // [256 dbl] bn scale a_f
#define WS_CD   55376    // [256 dbl] bn shift c_f
#define WS_WD   55888    // [16384 dbl] W' double [o][f]
#define WS_BPD  88656    // [64 dbl]  fused bias double

// ============================================================
// K1: BatchNorm batch stats per feature (fp64 accumulate) -> a_f, c_f doubles
// ============================================================
__global__ __launch_bounds__(256) void bn_stats(
    const float* __restrict__ x,
    const float* __restrict__ gamma,
    const float* __restrict__ beta,
    double* __restrict__ ad, double* __restrict__ cd)
{
    __shared__ double s1[256], s2[256];
    const int f = blockIdx.x, t = threadIdx.x;
    double s = 0.0, q = 0.0;
    for (int b = 0; b < 16; ++b) {
        const float4* p = (const float4*)(x + ((size_t)(b * 256 + f) << 12));
        for (int i = t; i < 1024; i += 256) {   // 1024 float4 = 4096 fp32
            float4 u = p[i];
            double dx = u.x, dy = u.y, dz = u.z, dw = u.w;
            s += dx + dy + dz + dw;
            q = fma(dx, dx, q); q = fma(dy, dy, q);
            q = fma(dz, dz, q); q = fma(dw, dw, q);
        }
    }
    s1[t] = s; s2[t] = q; __syncthreads();
    for (int st = 128; st; st >>= 1) {
        if (t < st) { s1[t] += s1[t + st]; s2[t] += s2[t + st]; }
        __syncthreads();
    }
    if (t == 0) {
        double mean = s1[0] * (1.0 / 65536.0);
        double var  = s2[0] * (1.0 / 65536.0) - mean * mean;
        double a = (double)gamma[f] / sqrt(var + 1e-5);
        ad[f] = a;
        cd[f] = (double)beta[f] - mean * a;
    }
}

// ============================================================
// K2a: W' = (conv2_w @ conv1_w) * a_f in fp64; float + double layouts
// ============================================================
__global__ __launch_bounds__(256) void prep_w(
    const float* __restrict__ w1,   // [64][256]
    const float* __restrict__ w2,   // [64][64]
    const double* __restrict__ ad,
    float* __restrict__ Wt,         // float [f][o]
    double* __restrict__ Wd)        // double [o][f]
{
    const int t = threadIdx.x;
    const int o = t & 63, fi = t >> 6;
    const int f = blockIdx.x * 4 + fi;
    double s = 0.0;
    for (int c = 0; c < 64; ++c)
        s = fma((double)w2[o * 64 + c], (double)w1[c * 256 + f], s);
    double wp = s * ad[f];
    Wd[o * 256 + f] = wp;
    Wt[f * 64 + o]  = (float)wp;
}

// ============================================================
// K2b: fp64 fused bias b', embedding transpose, norms, zero accs/counter
// ============================================================
__global__ __launch_bounds__(256) void prep_misc(
    const float* __restrict__ w1,
    const float* __restrict__ w2,
    const float* __restrict__ b1,
    const float* __restrict__ b2,
    const float* __restrict__ emb,  // [512][64] fp32
    const double* __restrict__ cd,
    float* __restrict__ bp, double* __restrict__ bpd,
    float* __restrict__ en, float* __restrict__ e2,
    float* __restrict__ eft, float* __restrict__ accs, int* __restrict__ cnt)
{
    __shared__ double red[4][64];
    __shared__ double tsh[64];
    const int t = threadIdx.x;
    const int o = t & 63, p = t >> 6;
    // t[c] = b1[c] + sum_f w1[c,f]*c_f   (partials over 64 f per sub-block)
    double s = 0.0;
    for (int j = 0; j < 64; ++j) {
        int fidx = p * 64 + j;
        s = fma((double)w1[o * 256 + fidx], cd[fidx], s);
    }
    red[p][o] = s; __syncthreads();
    if (t < 64) tsh[t] = (double)b1[t] + red[0][t] + red[1][t] + red[2][t] + red[3][t];
    __syncthreads();
    if (t < 64) {
        double bb = (double)b2[t];
        for (int c = 0; c < 64; ++c)
            bb = fma((double)w2[t * 64 + c], tsh[c], bb);
        bpd[t] = bb;
        bp[t]  = (float)bb;
    }
    for (int n = t; n < 512; n += 256) {
        float q = 0.f;
        for (int k = 0; k < 64; ++k) {
            float v = emb[n * 64 + k];
            eft[k * 512 + n] = v;
            q = fmaf(v, v, q);
        }
        e2[n] = q;
        en[n] = sqrtf(q);
    }
    if (t < 8) accs[t] = 0.f;
    if (t == 0) cnt[0] = 0;
}

// ============================================================
// K3: fused GEMM (z = x@W'^T + b') + VQ per (b,h) wave (fp32 fast path).
// lane = w; 64 channels = 64 tokens resolved in-wave. Near-ties flagged.
// ============================================================
__global__ __launch_bounds__(64, 1) void fused_gemm_vq(
    const float* __restrict__ x,
    const float* __restrict__ Wt,      // [256 f][64 o]
    const float* __restrict__ bp,      // [64]
    const float* __restrict__ emb,     // [512][64] fp32
    const float* __restrict__ e2,      // [512]
    float* __restrict__ accs,
    int* __restrict__ cnt, int* __restrict__ wl,
    float* __restrict__ zq)            // = out+1, fp32
{
    __shared__ float smem[64 * 65];    // Xs during GEMM, Zs during VQ
    const int lane = threadIdx.x;
    const int b = blockIdx.x >> 6;
    const int h = blockIdx.x & 63;

    float acc[64];
    #pragma unroll
    for (int c = 0; c < 64; ++c) acc[c] = 0.f;

    const float* xb = x + ((size_t)(b * 256) << 12) + (h << 6) + lane;

    for (int fc = 0; fc < 4; ++fc) {
        #pragma unroll
        for (int i = 0; i < 64; ++i)
            smem[i * 65 + lane] = xb[((size_t)(fc * 64 + i)) << 12];
        __syncthreads();
        const float* wp = Wt + fc * 64 * 64;
        #pragma unroll 1
        for (int i = 0; i < 64; ++i) {
            float xv = smem[i * 65 + lane];
            #pragma unroll
            for (int c = 0; c < 64; ++c)
                acc[c] = fmaf(wp[i * 64 + c], xv, acc[c]);   // wp uniform -> s_load
        }
        __syncthreads();
    }

    // bias + transpose via LDS: Zs[c][w]
    #pragma unroll
    for (int c = 0; c < 64; ++c) smem[c * 65 + lane] = acc[c] + bp[c];
    __syncthreads();

    float zr[64];
    #pragma unroll
    for (int k = 0; k < 64; ++k) zr[k] = smem[lane * 65 + k];
    float z2 = 0.f;
    #pragma unroll
    for (int k = 0; k < 64; ++k) z2 = fmaf(zr[k], zr[k], z2);

    float dmin = 3.4e38f, d2nd = 3.4e38f;
    int bidx = 0;
    #pragma unroll 1
    for (int n = 0; n < 512; ++n) {
        const float* ep = emb + (n << 6);                // uniform -> s_load
        float d0 = 0.f, d1 = 0.f, d2 = 0.f, d3 = 0.f;
        #pragma unroll
        for (int k = 0; k < 64; k += 4) {
            d0 = fmaf(zr[k + 0], ep[k + 0], d0);
            d1 = fmaf(zr[k + 1], ep[k + 1], d1);
            d2 = fmaf(zr[k + 2], ep[k + 2], d2);
            d3 = fmaf(zr[k + 3], ep[k + 3], d3);
        }
        float dot = (d0 + d1) + (d2 + d3);
        float d = z2 + e2[n] - 2.f * dot;
        if (d < dmin)      { d2nd = dmin; dmin = d; bidx = n; }
        else if (d < d2nd) { d2nd = d; }
    }

    // near-tie -> flag token for fp64 refinement
    if (d2nd - dmin < MARGIN) {
        int pos = atomicAdd(cnt, 1);
        if (pos < CAP) wl[pos] = ((b << 6) + lane) * 64 + h;
    }

    // mse accumulation: sum of d_min over tokens == sum((z_q - z)^2)
    float ms = dmin;
    #pragma unroll
    for (int off = 32; off; off >>= 1) ms += __shfl_xor(ms, off, 64);
    if (lane == 0) atomicAdd(accs + 0, ms);

    // z_q write: row c gets embedding[idx_c] fp32, coalesced over lanes
    float* zrow = zq + ((size_t)(b * 64) << 12) + (h << 6) + lane;
    #pragma unroll 1
    for (int c = 0; c < 64; ++c) {
        int id = __shfl(bidx, c, 64);
        zrow[(size_t)c << 12] = emb[(id << 6) + lane];
    }
}

// ============================================================
// K3b: fp64 refinement of flagged tokens (z from scratch, full 512 argmin)
// ============================================================
__global__ __launch_bounds__(256) void refine(
    const float* __restrict__ x,
    const double* __restrict__ Wd,     // [o][f] double
    const double* __restrict__ bpd,    // [64] double
    const float* __restrict__ emb,     // [512][64]
    const float* __restrict__ eft,     // [64][512]
    const int* __restrict__ cnt, const int* __restrict__ wl,
    float* __restrict__ zq)
{
    int count = cnt[0]; if (count > CAP) count = CAP;
    if ((int)blockIdx.x >= count) return;
    const int r = wl[blockIdx.x];
    const int b = r >> 12, c = (r >> 6) & 63, h = r & 63;
    const int tid = threadIdx.x, lane = tid & 63, wv = tid >> 6;

    __shared__ double zp[4][64];
    __shared__ double zs[64];
    __shared__ double dsh[256];
    __shared__ int    ish[256];

    // z[w=lane] in fp64; each of 4 waves covers 64 of the 256 features
    const float* xp = x + (((size_t)(b * 256 + wv * 64)) << 12) + (h << 6) + lane;
    const double* wrow = Wd + c * 256 + wv * 64;
    double zd = 0.0;
    #pragma unroll 8
    for (int f = 0; f < 64; ++f)
        zd = fma(wrow[f], (double)xp[((size_t)f) << 12], zd);
    zp[wv][lane] = zd;
    __syncthreads();
    if (tid < 64) zs[tid] = zp[0][tid] + zp[1][tid] + zp[2][tid] + zp[3][tid] + bpd[c];
    __syncthreads();

    // distances: 2 codes per thread, coalesced via eft [k][512]
    double dm = 1e300; int im = 0;
    #pragma unroll
    for (int jj = 0; jj < 2; ++jj) {
        int n = (jj << 8) + tid;
        double d = 0.0;
        #pragma unroll 8
        for (int k = 0; k < 64; ++k) {
            double t = zs[k] - (double)eft[(k << 9) + n];
            d = fma(t, t, d);
        }
        if (d < dm) { dm = d; im = n; }
    }
    dsh[tid] = dm; ish[tid] = im;
    __syncthreads();
    for (int st = 128; st; st >>= 1) {
        if (tid < st) {
            double od = dsh[tid + st]; int oi = ish[tid + st];
            if (od < dsh[tid] || (od == dsh[tid] && oi < ish[tid])) { dsh[tid] = od; ish[tid] = oi; }
        }
        __syncthreads();
    }
    if (tid < 64) {
        int idx = ish[0];
        zq[((size_t)r << 6) + tid] = emb[(idx << 6) + tid];
    }
}

// ============================================================
// K4: codebook angular stats (symmetric: col 2nd-min == row 2nd-min)
// ============================================================
__global__ __launch_bounds__(64) void cb_stats(
    const float* __restrict__ emb, const float* __restrict__ eft,
    const float* __restrict__ en, float* __restrict__ accs)
{
    __shared__ float ang[512];
    const int lane = threadIdx.x;
    const int i = blockIdx.x;
    const float eni = en[i];
    const float* ei = emb + (i << 6);    // uniform
    float m1 = 3.4e38f, m2 = 3.4e38f, ssum = 0.f;
    #pragma unroll 1
    for (int jj = 0; jj < 8; ++jj) {
        int j = (jj << 6) + lane;
        float d0 = 0.f, d1 = 0.f, d2 = 0.f, d3 = 0.f;
        #pragma unroll
        for (int k = 0; k < 64; k += 4) {
            d0 = fmaf(ei[k + 0], eft[(k + 0) * 512 + j], d0);
            d1 = fmaf(ei[k + 1], eft[(k + 1) * 512 + j], d1);
            d2 = fmaf(ei[k + 2], eft[(k + 2) * 512 + j], d2);
            d3 = fmaf(ei[k + 3], eft[(k + 3) * 512 + j], d3);
        }
        float dot = (d0 + d1) + (d2 + d3);
        float xv = dot / (eni * en[j]);
        xv = fminf(fmaxf(xv, -0.99999f), 0.99999f);
        float a = acosf(xv);
        ang[j] = a;
        ssum += a;
        if (a < m1) { m2 = m1; m1 = a; }
        else if (a < m2) m2 = a;
    }
    __syncthreads();
    #pragma unroll
    for (int off = 32; off; off >>= 1) ssum += __shfl_xor(ssum, off, 64);
    #pragma unroll
    for (int off = 32; off; off >>= 1) {
        float o1 = __shfl_xor(m1, off, 64);
        float o2 = __shfl_xor(m2, off, 64);
        if (o1 < m1) { m2 = fminf(m1, o2); m1 = o1; }
        else          m2 = fminf(m2, o1);
    }
    float mean = ssum * (1.f / 512.f);
    float vs = 0.f;
    #pragma unroll
    for (int jj = 0; jj < 8; ++jj) {
        float t = ang[(jj << 6) + lane] - mean;
        vs = fmaf(t, t, vs);
    }
    #pragma unroll
    for (int off = 32; off; off >>= 1) vs += __shfl_xor(vs, off, 64);
    if (lane == 0) {
        atomicAdd(accs + 1, vs * (1.f / 511.f));  // row variance (ddof=1)
        atomicAdd(accs + 2, m2);                  // row second-smallest
    }
}

// ============================================================
// K5: finalize scalars (fp32 out)
// ============================================================
__global__ __launch_bounds__(64) void finalize(
    const float* __restrict__ accs, const float* __restrict__ en,
    const float* __restrict__ r, float* __restrict__ out)
{
    const int lane = threadIdx.x;
    float hs = 0.f, rs = 0.f;
    #pragma unroll
    for (int jj = 0; jj < 8; ++jj) {
        int n = (jj << 6) + lane;
        float rv = r[n];
        float d = rv - en[n];
        hs = fmaf(d, d, hs);
        rs += fminf(fmaxf(rv, 0.9f), 1.1f);
    }
    #pragma unroll
    for (int off = 32; off; off >>= 1) { hs += __shfl_xor(hs, off, 64); rs += __shfl_xor(rs, off, 64); }
    if (lane == 0) {
        float hsw    = hs * (1.f / 512.f);
        float mean_r = rs * (1.f / 512.f);
        float mse    = accs[0] * (1.f / 4194304.f);
        float cbv    = accs[1] * (1.f / 512.f);
        float tmd    = accs[2] * (1.f / 512.f);
        float loss   = 2.f * mse + hsw + (cbv - tmd);   // beta=1 -> both commit terms equal
        out[0]       = loss;
        out[4194305] = cbv;
        out[4194306] = tmd;
        out[4194307] = hsw;
        out[4194308] = 0.f;                             // cb_loss = 0
        out[4194309] = mean_r;
    }
}

// ============================================================
extern "C" void kernel_launch(void* const* d_in, const int* in_sizes, int n_in,
                              void* d_out, int out_size, void* d_ws, size_t ws_size,
                              hipStream_t stream) {
    const float* x   = (const float*)d_in[0];
    const float* g1  = (const float*)d_in[1];
    const float* be1 = (const float*)d_in[2];
    const float* w1  = (const float*)d_in[3];
    const float* b1  = (const float*)d_in[4];
    const float* w2  = (const float*)d_in[5];
    const float* b2  = (const float*)d_in[6];
    const float* emb = (const float*)d_in[7];
    const float* r   = (const float*)d_in[8];
    float* ws = (float*)d_ws;
    float* out = (float*)d_out;

    double* AD  = (double*)(ws + WS_AD);
    double* CD  = (double*)(ws + WS_CD);
    double* WD  = (double*)(ws + WS_WD);
    double* BPD = (double*)(ws + WS_BPD);
    int*    CNT = (int*)(ws + WS_CNT);
    int*    WL  = (int*)(ws + WS_WL);

    bn_stats<<<256, 256, 0, stream>>>(x, g1, be1, AD, CD);
    prep_w<<<64, 256, 0, stream>>>(w1, w2, AD, ws + WS_WT, WD);
    prep_misc<<<1, 256, 0, stream>>>(w1, w2, b1, b2, emb, CD,
                                     ws + WS_BP, BPD, ws + WS_EN, ws + WS_E2,
                                     ws + WS_EFT, ws + WS_ACC, CNT);
    fused_gemm_vq<<<1024, 64, 0, stream>>>(x, ws + WS_WT, ws + WS_BP,
                                           emb, ws + WS_E2, ws + WS_ACC,
                                           CNT, WL, out + 1);
    refine<<<CAP, 256, 0, stream>>>(x, WD, BPD, emb, ws + WS_EFT, CNT, WL, out + 1);
    cb_stats<<<512, 64, 0, stream>>>(emb, ws + WS_EFT, ws + WS_EN, ws + WS_ACC);
    finalize<<<1, 64, 0, stream>>>(ws + WS_ACC, ws + WS_EN, r, out);
}